// Round 6
// baseline (6071.778 us; speedup 1.0000x reference)
//
#include <hip/hip_runtime.h>

#define NN 50000
#define EE 800000
#define TT 12
#define BB 2

// ws layout (4B units):
//  [0, 50048)            dinv
//  [50048, 2450048)      AX[b][n][t][f]  (BB*NN*TT*2 floats)
//  [2450048, 2454144)    P folded params: per gate g at g*1120:
//          [0:32) WF0, [32:64) WF1, [64:96) cF, [96+32k+j) LB[k][j]
//        probs at [3360:3372)
//  [2454144, 2504192)    cnt (int)
//  [2504192, 2554240)    off (int)
//  [2554240, 2604288)    cur (int)
//  [2604288, 2604416)    bsum (int)
// CSR payload lives in d_out (fully overwritten by k_recur at the end):
//  d_out[0..800000)        esrc (int)
//  d_out[800000..1600000)  ewgt (float)
#define OFF_AX   50048
#define OFF_P    2450048
#define OFF_CNT  2454144
#define OFF_OFF  2504192
#define OFF_CUR  2554240
#define OFF_BSUM 2604288
#define NB_SCAN  98  // ceil(50000/512)
#define PSZ      3372

__device__ __forceinline__ float fsig(float x) {
    x = fminf(fmaxf(x, -30.f), 30.f);
    return __builtin_amdgcn_rcpf(1.f + __expf(-x));
}
__device__ __forceinline__ float ftanh(float x) {
    x = fminf(fmaxf(x, -15.f), 15.f);
    float e = __expf(-2.f * x);
    return (1.f - e) * __builtin_amdgcn_rcpf(1.f + e);
}

__global__ void k_zero(int* __restrict__ cnt) {
    int i = blockIdx.x * 256 + threadIdx.x;
    if (i < NN) cnt[i] = 0;
}

__global__ void k_count(const int* __restrict__ idx, int* __restrict__ cnt) {
    int e = blockIdx.x * 256 + threadIdx.x;
    if (e < EE) atomicAdd(&cnt[idx[EE + e]], 1);
}

// exclusive scan of cnt -> off (per-block), block totals -> bsum
__global__ void k_scanA(const int* __restrict__ cnt, int* __restrict__ off,
                        int* __restrict__ bsum) {
    __shared__ int sm[512];
    int i = blockIdx.x * 512 + threadIdx.x;
    int v = (i < NN) ? cnt[i] : 0;
    sm[threadIdx.x] = v;
    __syncthreads();
#pragma unroll
    for (int d = 1; d < 512; d <<= 1) {
        int t = (threadIdx.x >= d) ? sm[threadIdx.x - d] : 0;
        __syncthreads();
        sm[threadIdx.x] += t;
        __syncthreads();
    }
    if (i < NN) off[i] = sm[threadIdx.x] - v;  // exclusive within block
    if (threadIdx.x == 511) bsum[blockIdx.x] = sm[511];
}

__global__ void k_scanB(int* __restrict__ bsum) {
    __shared__ int sm[128];
    int tid = threadIdx.x;
    int v = (tid < NB_SCAN) ? bsum[tid] : 0;
    sm[tid] = v;
    __syncthreads();
#pragma unroll
    for (int d = 1; d < 128; d <<= 1) {
        int t = (tid >= d) ? sm[tid - d] : 0;
        __syncthreads();
        sm[tid] += t;
        __syncthreads();
    }
    if (tid < NB_SCAN) bsum[tid] = sm[tid] - v;  // exclusive
}

__global__ void k_scanC(int* __restrict__ off, const int* __restrict__ bsum,
                        int* __restrict__ cur) {
    int i = blockIdx.x * 256 + threadIdx.x;
    if (i < NN) {
        int o = off[i] + bsum[i >> 9];
        off[i] = o;
        cur[i] = o;
    }
}

__global__ void k_fill(const int* __restrict__ idx, const float* __restrict__ w,
                       int* __restrict__ cur, int* __restrict__ esrc,
                       float* __restrict__ ewgt) {
    int e = blockIdx.x * 256 + threadIdx.x;
    if (e >= EE) return;
    int c = idx[EE + e];
    int s = atomicAdd(&cur[c], 1);
    esrc[s] = idx[e];
    ewgt[s] = w[e];
}

__global__ void k_degdinv(const int* __restrict__ off, const int* __restrict__ cnt,
                          const float* __restrict__ ewgt, float* __restrict__ dinv) {
    int n = blockIdx.x * 256 + threadIdx.x;
    if (n >= NN) return;
    int s0 = off[n], c = cnt[n];
    float d = 1.f;  // self loop
    for (int q = 0; q < c; q++) d += ewgt[s0 + q];
    dinv[n] = rsqrtf(d);
}

// AX[b][n][t][f] = dinv[n]^2 * X[b][n][f][t] + sum_in nrm * X[b][src][f][t]
__global__ __launch_bounds__(256) void k_gather(const float* __restrict__ X,
                                                const float* __restrict__ dinv,
                                                const int* __restrict__ esrc,
                                                const float* __restrict__ ewgt,
                                                const int* __restrict__ off,
                                                const int* __restrict__ cnt,
                                                float* __restrict__ AX) {
    int tid = blockIdx.x * 256 + threadIdx.x;  // b*NN + n
    if (tid >= BB * NN) return;
    int b = tid / NN;
    int n = tid - b * NN;
    float di = dinv[n];
    const float* Xb = X + (size_t)b * NN * 24;

    float xf[24], acc[24];
    {
        const float4* xs = (const float4*)(Xb + (size_t)n * 24);
        float s = di * di;
#pragma unroll
        for (int q = 0; q < 6; q++) {
            float4 v = xs[q];
            xf[4 * q] = v.x; xf[4 * q + 1] = v.y; xf[4 * q + 2] = v.z; xf[4 * q + 3] = v.w;
        }
#pragma unroll
        for (int t = 0; t < TT; t++) {
            acc[2 * t] = s * xf[t];
            acc[2 * t + 1] = s * xf[12 + t];
        }
    }
    int s0 = off[n], c = cnt[n];
    for (int q = 0; q < c; q++) {
        int r = esrc[s0 + q];
        float nrm = dinv[r] * ewgt[s0 + q] * di;
        const float4* xr = (const float4*)(Xb + (size_t)r * 24);
#pragma unroll
        for (int p = 0; p < 6; p++) {
            float4 v = xr[p];
            xf[4 * p] = v.x; xf[4 * p + 1] = v.y; xf[4 * p + 2] = v.z; xf[4 * p + 3] = v.w;
        }
#pragma unroll
        for (int t = 0; t < TT; t++) {
            acc[2 * t] = fmaf(nrm, xf[t], acc[2 * t]);
            acc[2 * t + 1] = fmaf(nrm, xf[12 + t], acc[2 * t + 1]);
        }
    }
    float4* o = (float4*)(AX + (size_t)tid * 24);
#pragma unroll
    for (int q = 0; q < 6; q++)
        o[q] = make_float4(acc[4 * q], acc[4 * q + 1], acc[4 * q + 2], acc[4 * q + 3]);
}

// fold weights: per gate g at base g*1120: WF0[j]=sum_k W[0][k]Lw[k][j], WF1, cF, LB[k][j]=Lw[32+k][j]
__global__ void k_fold(const float* __restrict__ Wz, const float* __restrict__ bz,
                       const float* __restrict__ Lwz, const float* __restrict__ Lbz,
                       const float* __restrict__ Wr, const float* __restrict__ br,
                       const float* __restrict__ Lwr, const float* __restrict__ Lbr,
                       const float* __restrict__ Wh, const float* __restrict__ bh,
                       const float* __restrict__ Lwh, const float* __restrict__ Lbh,
                       const float* __restrict__ att, float* __restrict__ P) {
    int tid = threadIdx.x;
    if (tid < 96) {
        int g = tid >> 5, j = tid & 31;
        const float* W  = g == 0 ? Wz  : (g == 1 ? Wr  : Wh);
        const float* b  = g == 0 ? bz  : (g == 1 ? br  : bh);
        const float* Lw = g == 0 ? Lwz : (g == 1 ? Lwr : Lwh);
        const float* Lb = g == 0 ? Lbz : (g == 1 ? Lbr : Lbh);
        float* out = P + g * 1120;
        float w0 = 0.f, w1 = 0.f, c = 0.f;
        for (int k = 0; k < 32; k++) {
            float lw = Lw[k * 32 + j];
            w0 += W[k] * lw;
            w1 += W[32 + k] * lw;
            c  += b[k] * lw;
        }
        out[j] = w0;
        out[32 + j] = w1;
        out[64 + j] = c + Lb[j];
        for (int k = 0; k < 32; k++) out[96 + k * 32 + j] = Lw[(32 + k) * 32 + j];
    } else if (tid == 96) {
        float m = -1e30f;
        for (int t = 0; t < TT; t++) m = fmaxf(m, att[t]);
        float s = 0.f;
        float e[TT];
        for (int t = 0; t < TT; t++) { e[t] = __expf(att[t] - m); s += e[t]; }
        for (int t = 0; t < TT; t++) P[3360 + t] = e[t] / s;
    }
}

// One thread per (b,n); all 32 channels in registers. Weights staged in LDS once
// per block and read with wave-uniform addresses (ds_read broadcast, conflict-free)
// -> weight delivery moves off the VALU/SMEM path onto the LDS pipe.
__global__ __launch_bounds__(64) void k_recur(const float* __restrict__ AX,
                                              const float* __restrict__ P,
                                              float* __restrict__ out) {
    __shared__ float sP[PSZ];
#pragma unroll
    for (int i = 0; i < 53; i++) {
        int o = i * 64 + threadIdx.x;
        if (o < PSZ) sP[o] = P[o];
    }
    __syncthreads();

    int tid = blockIdx.x * 64 + threadIdx.x;  // b*NN + n
    if (tid >= BB * NN) return;
    const float* pz = sP;
    const float* pr = sP + 1120;
    const float* ph = sP + 2240;
    const float* probs = sP + 3360;
    const float2* __restrict__ xa = (const float2*)(AX + (size_t)tid * 24);

    float H[32], acc[32];

    // t = 0: H == 0 -> z/h are init-only, H*R == 0 (r gate irrelevant).
    {
        float2 a = xa[0];
        float p = probs[0];
#pragma unroll
        for (int j = 0; j < 32; j++) {
            float z = fsig(fmaf(a.x, pz[j], fmaf(a.y, pz[32 + j], pz[64 + j])));
            float ht = ftanh(fmaf(a.x, ph[j], fmaf(a.y, ph[32 + j], ph[64 + j])));
            float hn = (1.f - z) * ht;
            H[j] = hn;
            acc[j] = p * hn;
        }
    }

#pragma unroll 1
    for (int t = 1; t < TT; t++) {
        float2 a = xa[t];
        float a0 = a.x, a1 = a.y;
        float z[32], r[32];
#pragma unroll
        for (int j = 0; j < 32; j++) z[j] = fmaf(a0, pz[j], fmaf(a1, pz[32 + j], pz[64 + j]));
#pragma unroll
        for (int j = 0; j < 32; j++) r[j] = fmaf(a0, pr[j], fmaf(a1, pr[32 + j], pr[64 + j]));
#pragma unroll
        for (int k = 0; k < 32; k++) {
            float hk = H[k];
#pragma unroll
            for (int j = 0; j < 32; j++) z[j] = fmaf(hk, pz[96 + 32 * k + j], z[j]);
#pragma unroll
            for (int j = 0; j < 32; j++) r[j] = fmaf(hk, pr[96 + 32 * k + j], r[j]);
        }
#pragma unroll
        for (int j = 0; j < 32; j++) {
            z[j] = fsig(z[j]);
            r[j] = fsig(r[j]) * H[j];  // r now holds H*R
        }
        float h[32];
#pragma unroll
        for (int j = 0; j < 32; j++) h[j] = fmaf(a0, ph[j], fmaf(a1, ph[32 + j], ph[64 + j]));
#pragma unroll
        for (int k = 0; k < 32; k++) {
            float hk = r[k];
#pragma unroll
            for (int j = 0; j < 32; j++) h[j] = fmaf(hk, ph[96 + 32 * k + j], h[j]);
        }
        float p = probs[t];
#pragma unroll
        for (int j = 0; j < 32; j++) {
            float ht = ftanh(h[j]);
            float hn = fmaf(z[j], H[j] - ht, ht);  // z*H + (1-z)*ht
            H[j] = hn;
            acc[j] = fmaf(p, hn, acc[j]);
        }
    }
    float4* o = (float4*)(out + (size_t)tid * 32);
#pragma unroll
    for (int q = 0; q < 8; q++)
        o[q] = make_float4(acc[4 * q], acc[4 * q + 1], acc[4 * q + 2], acc[4 * q + 3]);
}

extern "C" void kernel_launch(void* const* d_in, const int* in_sizes, int n_in,
                              void* d_out, int out_size, void* d_ws, size_t ws_size,
                              hipStream_t stream) {
    const float* X   = (const float*)d_in[0];
    const int*   idx = (const int*)d_in[1];
    const float* ew  = (const float*)d_in[2];
    const float* Wz  = (const float*)d_in[3];
    const float* bz  = (const float*)d_in[4];
    const float* Wr  = (const float*)d_in[5];
    const float* br  = (const float*)d_in[6];
    const float* Wh  = (const float*)d_in[7];
    const float* bh  = (const float*)d_in[8];
    const float* Lwz = (const float*)d_in[9];
    const float* Lbz = (const float*)d_in[10];
    const float* Lwr = (const float*)d_in[11];
    const float* Lbr = (const float*)d_in[12];
    const float* Lwh = (const float*)d_in[13];
    const float* Lbh = (const float*)d_in[14];
    const float* att = (const float*)d_in[15];

    float* ws   = (float*)d_ws;
    float* dinv = ws;
    float* AX   = ws + OFF_AX;
    float* P    = ws + OFF_P;
    int*   cnt  = (int*)ws + OFF_CNT;
    int*   off  = (int*)ws + OFF_OFF;
    int*   cur  = (int*)ws + OFF_CUR;
    int*   bsum = (int*)ws + OFF_BSUM;
    float* out  = (float*)d_out;
    int*   esrc = (int*)d_out;              // scratch inside d_out
    float* ewgt = (float*)d_out + EE;       // scratch inside d_out

    hipLaunchKernelGGL(k_zero, dim3((NN + 255) / 256), dim3(256), 0, stream, cnt);
    hipLaunchKernelGGL(k_count, dim3((EE + 255) / 256), dim3(256), 0, stream, idx, cnt);
    hipLaunchKernelGGL(k_scanA, dim3(NB_SCAN), dim3(512), 0, stream, cnt, off, bsum);
    hipLaunchKernelGGL(k_scanB, dim3(1), dim3(128), 0, stream, bsum);
    hipLaunchKernelGGL(k_scanC, dim3((NN + 255) / 256), dim3(256), 0, stream, off, bsum, cur);
    hipLaunchKernelGGL(k_fill, dim3((EE + 255) / 256), dim3(256), 0, stream, idx, ew, cur, esrc, ewgt);
    hipLaunchKernelGGL(k_degdinv, dim3((NN + 255) / 256), dim3(256), 0, stream, off, cnt, ewgt, dinv);
    hipLaunchKernelGGL(k_gather, dim3((BB * NN + 255) / 256), dim3(256), 0, stream,
                       X, dinv, esrc, ewgt, off, cnt, AX);
    hipLaunchKernelGGL(k_fold, dim3(1), dim3(128), 0, stream,
                       Wz, bz, Lwz, Lbz, Wr, br, Lwr, Lbr, Wh, bh, Lwh, Lbh, att, P);
    hipLaunchKernelGGL(k_recur, dim3((BB * NN + 63) / 64), dim3(64), 0, stream, AX, P, out);
}

// Round 7
// 566.314 us; speedup vs baseline: 10.7216x; 10.7216x over previous
//
#include <hip/hip_runtime.h>

#define NN 50000
#define EE 800000
#define TT 12
#define BB 2

// ws layout (4B units):
//  [0, 50048)            dinv
//  [50048, 2450048)      AX[b][n][t][f]  (BB*NN*TT*2 floats)
//  [2450048, 2454144)    P folded params: per gate g at g*1120:
//          [0:32) WF0, [32:64) WF1, [64:96) cF, [96+32k+j) LB[k][j]
//        probs at [3360:3372)
//  [2454144, 2504192)    cnt (int)
//  [2504192, 2554240)    off (int)
//  [2554240, 2604288)    cur (int)
//  [2604288, 2604416)    bsum (int)
// CSR payload lives in d_out (fully overwritten by k_recur at the end):
//  d_out[0..800000)        esrc (int)
//  d_out[800000..1600000)  ewgt (float)
#define OFF_AX   50048
#define OFF_P    2450048
#define OFF_CNT  2454144
#define OFF_OFF  2504192
#define OFF_CUR  2554240
#define OFF_BSUM 2604288
#define NB_SCAN  98  // ceil(50000/512)

__device__ __forceinline__ float fsig(float x) {
    x = fminf(fmaxf(x, -30.f), 30.f);
    return __builtin_amdgcn_rcpf(1.f + __expf(-x));
}
__device__ __forceinline__ float ftanh(float x) {
    x = fminf(fmaxf(x, -15.f), 15.f);
    float e = __expf(-2.f * x);
    return (1.f - e) * __builtin_amdgcn_rcpf(1.f + e);
}

__global__ void k_zero(int* __restrict__ cnt) {
    int i = blockIdx.x * 256 + threadIdx.x;
    if (i < NN) cnt[i] = 0;
}

__global__ void k_count(const int* __restrict__ idx, int* __restrict__ cnt) {
    int e = blockIdx.x * 256 + threadIdx.x;
    if (e < EE) atomicAdd(&cnt[idx[EE + e]], 1);
}

// exclusive scan of cnt -> off (per-block), block totals -> bsum
__global__ void k_scanA(const int* __restrict__ cnt, int* __restrict__ off,
                        int* __restrict__ bsum) {
    __shared__ int sm[512];
    int i = blockIdx.x * 512 + threadIdx.x;
    int v = (i < NN) ? cnt[i] : 0;
    sm[threadIdx.x] = v;
    __syncthreads();
#pragma unroll
    for (int d = 1; d < 512; d <<= 1) {
        int t = (threadIdx.x >= d) ? sm[threadIdx.x - d] : 0;
        __syncthreads();
        sm[threadIdx.x] += t;
        __syncthreads();
    }
    if (i < NN) off[i] = sm[threadIdx.x] - v;  // exclusive within block
    if (threadIdx.x == 511) bsum[blockIdx.x] = sm[511];
}

__global__ void k_scanB(int* __restrict__ bsum) {
    __shared__ int sm[128];
    int tid = threadIdx.x;
    int v = (tid < NB_SCAN) ? bsum[tid] : 0;
    sm[tid] = v;
    __syncthreads();
#pragma unroll
    for (int d = 1; d < 128; d <<= 1) {
        int t = (tid >= d) ? sm[tid - d] : 0;
        __syncthreads();
        sm[tid] += t;
        __syncthreads();
    }
    if (tid < NB_SCAN) bsum[tid] = sm[tid] - v;  // exclusive
}

__global__ void k_scanC(int* __restrict__ off, const int* __restrict__ bsum,
                        int* __restrict__ cur) {
    int i = blockIdx.x * 256 + threadIdx.x;
    if (i < NN) {
        int o = off[i] + bsum[i >> 9];
        off[i] = o;
        cur[i] = o;
    }
}

__global__ void k_fill(const int* __restrict__ idx, const float* __restrict__ w,
                       int* __restrict__ cur, int* __restrict__ esrc,
                       float* __restrict__ ewgt) {
    int e = blockIdx.x * 256 + threadIdx.x;
    if (e >= EE) return;
    int c = idx[EE + e];
    int s = atomicAdd(&cur[c], 1);
    esrc[s] = idx[e];
    ewgt[s] = w[e];
}

__global__ void k_degdinv(const int* __restrict__ off, const int* __restrict__ cnt,
                          const float* __restrict__ ewgt, float* __restrict__ dinv) {
    int n = blockIdx.x * 256 + threadIdx.x;
    if (n >= NN) return;
    int s0 = off[n], c = cnt[n];
    float d = 1.f;  // self loop
    for (int q = 0; q < c; q++) d += ewgt[s0 + q];
    dinv[n] = rsqrtf(d);
}

// AX[b][n][t][f] = dinv[n]^2 * X[b][n][f][t] + sum_in nrm * X[b][src][f][t]
__global__ __launch_bounds__(256) void k_gather(const float* __restrict__ X,
                                                const float* __restrict__ dinv,
                                                const int* __restrict__ esrc,
                                                const float* __restrict__ ewgt,
                                                const int* __restrict__ off,
                                                const int* __restrict__ cnt,
                                                float* __restrict__ AX) {
    int tid = blockIdx.x * 256 + threadIdx.x;  // b*NN + n
    if (tid >= BB * NN) return;
    int b = tid / NN;
    int n = tid - b * NN;
    float di = dinv[n];
    const float* Xb = X + (size_t)b * NN * 24;

    float xf[24], acc[24];
    {
        const float4* xs = (const float4*)(Xb + (size_t)n * 24);
        float s = di * di;
#pragma unroll
        for (int q = 0; q < 6; q++) {
            float4 v = xs[q];
            xf[4 * q] = v.x; xf[4 * q + 1] = v.y; xf[4 * q + 2] = v.z; xf[4 * q + 3] = v.w;
        }
#pragma unroll
        for (int t = 0; t < TT; t++) {
            acc[2 * t] = s * xf[t];
            acc[2 * t + 1] = s * xf[12 + t];
        }
    }
    int s0 = off[n], c = cnt[n];
    for (int q = 0; q < c; q++) {
        int r = esrc[s0 + q];
        float nrm = dinv[r] * ewgt[s0 + q] * di;
        const float4* xr = (const float4*)(Xb + (size_t)r * 24);
#pragma unroll
        for (int p = 0; p < 6; p++) {
            float4 v = xr[p];
            xf[4 * p] = v.x; xf[4 * p + 1] = v.y; xf[4 * p + 2] = v.z; xf[4 * p + 3] = v.w;
        }
#pragma unroll
        for (int t = 0; t < TT; t++) {
            acc[2 * t] = fmaf(nrm, xf[t], acc[2 * t]);
            acc[2 * t + 1] = fmaf(nrm, xf[12 + t], acc[2 * t + 1]);
        }
    }
    float4* o = (float4*)(AX + (size_t)tid * 24);
#pragma unroll
    for (int q = 0; q < 6; q++)
        o[q] = make_float4(acc[4 * q], acc[4 * q + 1], acc[4 * q + 2], acc[4 * q + 3]);
}

// fold weights: per gate g at base g*1120: WF0[j]=sum_k W[0][k]Lw[k][j], WF1, cF, LB[k][j]=Lw[32+k][j]
__global__ void k_fold(const float* __restrict__ Wz, const float* __restrict__ bz,
                       const float* __restrict__ Lwz, const float* __restrict__ Lbz,
                       const float* __restrict__ Wr, const float* __restrict__ br,
                       const float* __restrict__ Lwr, const float* __restrict__ Lbr,
                       const float* __restrict__ Wh, const float* __restrict__ bh,
                       const float* __restrict__ Lwh, const float* __restrict__ Lbh,
                       const float* __restrict__ att, float* __restrict__ P) {
    int tid = threadIdx.x;
    if (tid < 96) {
        int g = tid >> 5, j = tid & 31;
        const float* W  = g == 0 ? Wz  : (g == 1 ? Wr  : Wh);
        const float* b  = g == 0 ? bz  : (g == 1 ? br  : bh);
        const float* Lw = g == 0 ? Lwz : (g == 1 ? Lwr : Lwh);
        const float* Lb = g == 0 ? Lbz : (g == 1 ? Lbr : Lbh);
        float* out = P + g * 1120;
        float w0 = 0.f, w1 = 0.f, c = 0.f;
        for (int k = 0; k < 32; k++) {
            float lw = Lw[k * 32 + j];
            w0 += W[k] * lw;
            w1 += W[32 + k] * lw;
            c  += b[k] * lw;
        }
        out[j] = w0;
        out[32 + j] = w1;
        out[64 + j] = c + Lb[j];
        for (int k = 0; k < 32; k++) out[96 + k * 32 + j] = Lw[(32 + k) * 32 + j];
    } else if (tid == 96) {
        float m = -1e30f;
        for (int t = 0; t < TT; t++) m = fmaxf(m, att[t]);
        float s = 0.f;
        float e[TT];
        for (int t = 0; t < TT; t++) { e[t] = __expf(att[t] - m); s += e[t]; }
        for (int t = 0; t < TT; t++) P[3360 + t] = e[t] / s;
    }
}

// One thread per (b,n). Gate order r -> h -> z keeps peak live floats at
// H(32) + two gate arrays(64) ~= 96 (vs 160 when z,r,h coexist) -> fits VGPRs,
// no AGPR spill-copy storm. acc lives in thread-private LDS column (touched
// once per t; conflict-free stride-64, 2-way wave64 aliasing is free).
// Weights stay on the scalar path: wave-uniform global loads -> s_load.
__global__ __launch_bounds__(64) void k_recur(const float* __restrict__ AX,
                                              const float* __restrict__ P,
                                              float* __restrict__ out) {
    __shared__ float accL[32][64];  // 8 KB
    int lt = threadIdx.x;
    int tid = blockIdx.x * 64 + lt;  // b*NN + n
    if (tid >= BB * NN) return;
    const float* __restrict__ pz = P;
    const float* __restrict__ pr = P + 1120;
    const float* __restrict__ ph = P + 2240;
    const float* __restrict__ probs = P + 3360;
    const float2* __restrict__ xa = (const float2*)(AX + (size_t)tid * 24);

    float H[32];

    // t = 0: H == 0 -> z/h are init-only; r irrelevant (H*R == 0).
    {
        float2 a = xa[0];
        float p = probs[0];
#pragma unroll
        for (int j = 0; j < 32; j++) {
            float z = fsig(fmaf(a.x, pz[j], fmaf(a.y, pz[32 + j], pz[64 + j])));
            float ht = ftanh(fmaf(a.x, ph[j], fmaf(a.y, ph[32 + j], ph[64 + j])));
            float hn = (1.f - z) * ht;
            H[j] = hn;
            accL[j][lt] = p * hn;
        }
    }

#pragma unroll 1
    for (int t = 1; t < TT; t++) {
        float2 a = xa[t];
        float a0 = a.x, a1 = a.y;

        // r-gate matvec; fold into rH = fsig(r) * H  (stored in g)
        float g[32];
#pragma unroll
        for (int j = 0; j < 32; j++) g[j] = fmaf(a0, pr[j], fmaf(a1, pr[32 + j], pr[64 + j]));
#pragma unroll
        for (int k = 0; k < 32; k++) {
            float hk = H[k];
#pragma unroll
            for (int j = 0; j < 32; j++) g[j] = fmaf(hk, pr[96 + 32 * k + j], g[j]);
        }
#pragma unroll
        for (int j = 0; j < 32; j++) g[j] = fsig(g[j]) * H[j];  // g = H*R

        // h-gate matvec from g; h = tanh(...)  (g dead after)
        float h[32];
#pragma unroll
        for (int j = 0; j < 32; j++) h[j] = fmaf(a0, ph[j], fmaf(a1, ph[32 + j], ph[64 + j]));
#pragma unroll
        for (int k = 0; k < 32; k++) {
            float rk = g[k];
#pragma unroll
            for (int j = 0; j < 32; j++) h[j] = fmaf(rk, ph[96 + 32 * k + j], h[j]);
        }
#pragma unroll
        for (int j = 0; j < 32; j++) h[j] = ftanh(h[j]);

        // z-gate matvec into g (reuses storage)
#pragma unroll
        for (int j = 0; j < 32; j++) g[j] = fmaf(a0, pz[j], fmaf(a1, pz[32 + j], pz[64 + j]));
#pragma unroll
        for (int k = 0; k < 32; k++) {
            float hk = H[k];
#pragma unroll
            for (int j = 0; j < 32; j++) g[j] = fmaf(hk, pz[96 + 32 * k + j], g[j]);
        }

        // combine
        float p = probs[t];
#pragma unroll
        for (int j = 0; j < 32; j++) {
            float z = fsig(g[j]);
            float hn = fmaf(z, H[j] - h[j], h[j]);  // z*H + (1-z)*h
            H[j] = hn;
            accL[j][lt] = fmaf(p, hn, accL[j][lt]);
        }
    }

    float* o = out + (size_t)tid * 32;
#pragma unroll
    for (int j = 0; j < 32; j++) o[j] = accL[j][lt];
}

extern "C" void kernel_launch(void* const* d_in, const int* in_sizes, int n_in,
                              void* d_out, int out_size, void* d_ws, size_t ws_size,
                              hipStream_t stream) {
    const float* X   = (const float*)d_in[0];
    const int*   idx = (const int*)d_in[1];
    const float* ew  = (const float*)d_in[2];
    const float* Wz  = (const float*)d_in[3];
    const float* bz  = (const float*)d_in[4];
    const float* Wr  = (const float*)d_in[5];
    const float* br  = (const float*)d_in[6];
    const float* Wh  = (const float*)d_in[7];
    const float* bh  = (const float*)d_in[8];
    const float* Lwz = (const float*)d_in[9];
    const float* Lbz = (const float*)d_in[10];
    const float* Lwr = (const float*)d_in[11];
    const float* Lbr = (const float*)d_in[12];
    const float* Lwh = (const float*)d_in[13];
    const float* Lbh = (const float*)d_in[14];
    const float* att = (const float*)d_in[15];

    float* ws   = (float*)d_ws;
    float* dinv = ws;
    float* AX   = ws + OFF_AX;
    float* P    = ws + OFF_P;
    int*   cnt  = (int*)ws + OFF_CNT;
    int*   off  = (int*)ws + OFF_OFF;
    int*   cur  = (int*)ws + OFF_CUR;
    int*   bsum = (int*)ws + OFF_BSUM;
    float* out  = (float*)d_out;
    int*   esrc = (int*)d_out;              // scratch inside d_out
    float* ewgt = (float*)d_out + EE;       // scratch inside d_out

    hipLaunchKernelGGL(k_zero, dim3((NN + 255) / 256), dim3(256), 0, stream, cnt);
    hipLaunchKernelGGL(k_count, dim3((EE + 255) / 256), dim3(256), 0, stream, idx, cnt);
    hipLaunchKernelGGL(k_scanA, dim3(NB_SCAN), dim3(512), 0, stream, cnt, off, bsum);
    hipLaunchKernelGGL(k_scanB, dim3(1), dim3(128), 0, stream, bsum);
    hipLaunchKernelGGL(k_scanC, dim3((NN + 255) / 256), dim3(256), 0, stream, off, bsum, cur);
    hipLaunchKernelGGL(k_fill, dim3((EE + 255) / 256), dim3(256), 0, stream, idx, ew, cur, esrc, ewgt);
    hipLaunchKernelGGL(k_degdinv, dim3((NN + 255) / 256), dim3(256), 0, stream, off, cnt, ewgt, dinv);
    hipLaunchKernelGGL(k_gather, dim3((BB * NN + 255) / 256), dim3(256), 0, stream,
                       X, dinv, esrc, ewgt, off, cnt, AX);
    hipLaunchKernelGGL(k_fold, dim3(1), dim3(128), 0, stream,
                       Wz, bz, Lwz, Lbz, Wr, br, Lwr, Lbr, Wh, bh, Lwh, Lbh, att, P);
    hipLaunchKernelGGL(k_recur, dim3((BB * NN + 63) / 64), dim3(64), 0, stream, AX, P, out);
}

// Round 8
// 504.559 us; speedup vs baseline: 12.0338x; 1.1224x over previous
//
#include <hip/hip_runtime.h>

#define NN 50000
#define EE 800000
#define TT 12
#define BB 2

// ws layout (4B units):
//  [0, 50048)            dinv
//  [50048, 2450048)      AX[b][n][t][f]  (BB*NN*TT*2 floats)
//  [2450048, 2454144)    P folded params:
//        per (gate g, half q) block of 560 floats at (g*2+q)*560:
//          [0:16) WF0, [16:32) WF1, [32:48) cF, [48+k*16+jj) LB[k][q*16+jj]
//        probs at [3360:3372)
//  [2454144, 2504192)    cnt (int)
//  [2504192, 2554240)    off (int)
//  [2554240, 2604288)    cur (int)
//  [2604288, 2604416)    bsum (int)
// CSR payload lives in d_out (fully overwritten by k_recur at the end):
//  d_out[0..800000)        esrc (int)
//  d_out[800000..1600000)  ewgt (float)
#define OFF_AX   50048
#define OFF_P    2450048
#define OFF_CNT  2454144
#define OFF_OFF  2504192
#define OFF_CUR  2554240
#define OFF_BSUM 2604288
#define NB_SCAN  98  // ceil(50000/512)

__device__ __forceinline__ float fsig(float x) {
    x = fminf(fmaxf(x, -30.f), 30.f);
    return __builtin_amdgcn_rcpf(1.f + __expf(-x));
}
__device__ __forceinline__ float ftanh(float x) {
    x = fminf(fmaxf(x, -15.f), 15.f);
    float e = __expf(-2.f * x);
    return (1.f - e) * __builtin_amdgcn_rcpf(1.f + e);
}

__global__ void k_zero(int* __restrict__ cnt) {
    int i = blockIdx.x * 256 + threadIdx.x;
    if (i < NN) cnt[i] = 0;
}

__global__ void k_count(const int* __restrict__ idx, int* __restrict__ cnt) {
    int e = blockIdx.x * 256 + threadIdx.x;
    if (e < EE) atomicAdd(&cnt[idx[EE + e]], 1);
}

// exclusive scan of cnt -> off (per-block), block totals -> bsum
__global__ void k_scanA(const int* __restrict__ cnt, int* __restrict__ off,
                        int* __restrict__ bsum) {
    __shared__ int sm[512];
    int i = blockIdx.x * 512 + threadIdx.x;
    int v = (i < NN) ? cnt[i] : 0;
    sm[threadIdx.x] = v;
    __syncthreads();
#pragma unroll
    for (int d = 1; d < 512; d <<= 1) {
        int t = (threadIdx.x >= d) ? sm[threadIdx.x - d] : 0;
        __syncthreads();
        sm[threadIdx.x] += t;
        __syncthreads();
    }
    if (i < NN) off[i] = sm[threadIdx.x] - v;  // exclusive within block
    if (threadIdx.x == 511) bsum[blockIdx.x] = sm[511];
}

__global__ void k_scanB(int* __restrict__ bsum) {
    __shared__ int sm[128];
    int tid = threadIdx.x;
    int v = (tid < NB_SCAN) ? bsum[tid] : 0;
    sm[tid] = v;
    __syncthreads();
#pragma unroll
    for (int d = 1; d < 128; d <<= 1) {
        int t = (tid >= d) ? sm[tid - d] : 0;
        __syncthreads();
        sm[tid] += t;
        __syncthreads();
    }
    if (tid < NB_SCAN) bsum[tid] = sm[tid] - v;  // exclusive
}

__global__ void k_scanC(int* __restrict__ off, const int* __restrict__ bsum,
                        int* __restrict__ cur) {
    int i = blockIdx.x * 256 + threadIdx.x;
    if (i < NN) {
        int o = off[i] + bsum[i >> 9];
        off[i] = o;
        cur[i] = o;
    }
}

__global__ void k_fill(const int* __restrict__ idx, const float* __restrict__ w,
                       int* __restrict__ cur, int* __restrict__ esrc,
                       float* __restrict__ ewgt) {
    int e = blockIdx.x * 256 + threadIdx.x;
    if (e >= EE) return;
    int c = idx[EE + e];
    int s = atomicAdd(&cur[c], 1);
    esrc[s] = idx[e];
    ewgt[s] = w[e];
}

__global__ void k_degdinv(const int* __restrict__ off, const int* __restrict__ cnt,
                          const float* __restrict__ ewgt, float* __restrict__ dinv) {
    int n = blockIdx.x * 256 + threadIdx.x;
    if (n >= NN) return;
    int s0 = off[n], c = cnt[n];
    float d = 1.f;  // self loop
    for (int q = 0; q < c; q++) d += ewgt[s0 + q];
    dinv[n] = rsqrtf(d);
}

// AX[b][n][t][f] = dinv[n]^2 * X[b][n][f][t] + sum_in nrm * X[b][src][f][t]
__global__ __launch_bounds__(256) void k_gather(const float* __restrict__ X,
                                                const float* __restrict__ dinv,
                                                const int* __restrict__ esrc,
                                                const float* __restrict__ ewgt,
                                                const int* __restrict__ off,
                                                const int* __restrict__ cnt,
                                                float* __restrict__ AX) {
    int tid = blockIdx.x * 256 + threadIdx.x;  // b*NN + n
    if (tid >= BB * NN) return;
    int b = tid / NN;
    int n = tid - b * NN;
    float di = dinv[n];
    const float* Xb = X + (size_t)b * NN * 24;

    float xf[24], acc[24];
    {
        const float4* xs = (const float4*)(Xb + (size_t)n * 24);
        float s = di * di;
#pragma unroll
        for (int q = 0; q < 6; q++) {
            float4 v = xs[q];
            xf[4 * q] = v.x; xf[4 * q + 1] = v.y; xf[4 * q + 2] = v.z; xf[4 * q + 3] = v.w;
        }
#pragma unroll
        for (int t = 0; t < TT; t++) {
            acc[2 * t] = s * xf[t];
            acc[2 * t + 1] = s * xf[12 + t];
        }
    }
    int s0 = off[n], c = cnt[n];
    for (int q = 0; q < c; q++) {
        int r = esrc[s0 + q];
        float nrm = dinv[r] * ewgt[s0 + q] * di;
        const float4* xr = (const float4*)(Xb + (size_t)r * 24);
#pragma unroll
        for (int p = 0; p < 6; p++) {
            float4 v = xr[p];
            xf[4 * p] = v.x; xf[4 * p + 1] = v.y; xf[4 * p + 2] = v.z; xf[4 * p + 3] = v.w;
        }
#pragma unroll
        for (int t = 0; t < TT; t++) {
            acc[2 * t] = fmaf(nrm, xf[t], acc[2 * t]);
            acc[2 * t + 1] = fmaf(nrm, xf[12 + t], acc[2 * t + 1]);
        }
    }
    float4* o = (float4*)(AX + (size_t)tid * 24);
#pragma unroll
    for (int q = 0; q < 6; q++)
        o[q] = make_float4(acc[4 * q], acc[4 * q + 1], acc[4 * q + 2], acc[4 * q + 3]);
}

// fold weights into per-(gate,half) blocks:
//   base=(g*2+q)*560: [0:16) WF0, [16:32) WF1, [32:48) cF, [48+k*16+jj] LB[k][q*16+jj]
__global__ void k_fold(const float* __restrict__ Wz, const float* __restrict__ bz,
                       const float* __restrict__ Lwz, const float* __restrict__ Lbz,
                       const float* __restrict__ Wr, const float* __restrict__ br,
                       const float* __restrict__ Lwr, const float* __restrict__ Lbr,
                       const float* __restrict__ Wh, const float* __restrict__ bh,
                       const float* __restrict__ Lwh, const float* __restrict__ Lbh,
                       const float* __restrict__ att, float* __restrict__ P) {
    int tid = threadIdx.x;
    if (tid < 96) {
        int g = tid >> 5, j = tid & 31;
        int q = j >> 4, jj = j & 15;
        const float* W  = g == 0 ? Wz  : (g == 1 ? Wr  : Wh);
        const float* b  = g == 0 ? bz  : (g == 1 ? br  : bh);
        const float* Lw = g == 0 ? Lwz : (g == 1 ? Lwr : Lwh);
        const float* Lb = g == 0 ? Lbz : (g == 1 ? Lbr : Lbh);
        float* out = P + (g * 2 + q) * 560;
        float w0 = 0.f, w1 = 0.f, c = 0.f;
        for (int k = 0; k < 32; k++) {
            float lw = Lw[k * 32 + j];
            w0 += W[k] * lw;
            w1 += W[32 + k] * lw;
            c  += b[k] * lw;
        }
        out[jj] = w0;
        out[16 + jj] = w1;
        out[32 + jj] = c + Lb[j];
        for (int k = 0; k < 32; k++) out[48 + k * 16 + jj] = Lw[(32 + k) * 32 + j];
    } else if (tid == 96) {
        float m = -1e30f;
        for (int t = 0; t < TT; t++) m = fmaxf(m, att[t]);
        float s = 0.f;
        float e[TT];
        for (int t = 0; t < TT; t++) { e[t] = __expf(att[t] - m); s += e[t]; }
        for (int t = 0; t < TT; t++) P[3360 + t] = e[t] / s;
    }
}

// 2 waves per block; wave q owns j-half q of the block's 64 nodes. Weight indices
// wave-uniform (SGPR broadcast; 16 dwords/k -> batches double-buffer in SGPRs).
// H / H*R halves exchanged via LDS (double-buffered Hbuf -> 2 barriers/t), read
// per-k inside the unrolled loops (R7's proven clean-codegen pattern).
// No min-waves launch-bounds hint (R3/R4 spill trigger).
__global__ __launch_bounds__(128) void k_recur(const float* __restrict__ AX,
                                               const float* __restrict__ P,
                                               float* __restrict__ out) {
    __shared__ float Hbuf[2][32][64];  // 16 KB
    __shared__ float Rbuf[32][64];     // 8 KB
    int nl = threadIdx.x & 63;
    int q  = threadIdx.x >> 6;  // wave id = j-half, wave-uniform
    int qu = __builtin_amdgcn_readfirstlane(q);
    int node = blockIdx.x * 64 + nl;  // composite b*NN+n
    bool valid = node < BB * NN;
    int cn = valid ? node : BB * NN - 1;
    const float* __restrict__ pz = P + qu * 560;
    const float* __restrict__ pr = P + (2 + qu) * 560;
    const float* __restrict__ ph = P + (4 + qu) * 560;
    const float* __restrict__ probs = P + 3360;
    const float2* __restrict__ xa = (const float2*)(AX + (size_t)cn * 24);

    float Hown[16], acc[16];

    // t = 0: H == 0 -> z/h init-only; H*R == 0 (r irrelevant).
    {
        float2 a = xa[0];
        float p = probs[0];
#pragma unroll
        for (int jj = 0; jj < 16; jj++) {
            float z = fsig(fmaf(a.x, pz[jj], fmaf(a.y, pz[16 + jj], pz[32 + jj])));
            float ht = ftanh(fmaf(a.x, ph[jj], fmaf(a.y, ph[16 + jj], ph[32 + jj])));
            float hn = (1.f - z) * ht;
            Hown[jj] = hn;
            acc[jj] = p * hn;
            Hbuf[0][qu * 16 + jj][nl] = hn;
        }
    }
    __syncthreads();

    int cur = 0;
#pragma unroll 1
    for (int t = 1; t < TT; t++) {
        float2 a = xa[t];
        float g[16];
        // r-gate matvec (reads Hbuf[cur])
#pragma unroll
        for (int jj = 0; jj < 16; jj++) g[jj] = fmaf(a.x, pr[jj], fmaf(a.y, pr[16 + jj], pr[32 + jj]));
#pragma unroll
        for (int k = 0; k < 32; k++) {
            float hk = Hbuf[cur][k][nl];
#pragma unroll
            for (int jj = 0; jj < 16; jj++) g[jj] = fmaf(hk, pr[48 + k * 16 + jj], g[jj]);
        }
#pragma unroll
        for (int jj = 0; jj < 16; jj++) Rbuf[qu * 16 + jj][nl] = fsig(g[jj]) * Hown[jj];
        __syncthreads();

        // h-gate matvec (reads Rbuf)
        float h[16];
#pragma unroll
        for (int jj = 0; jj < 16; jj++) h[jj] = fmaf(a.x, ph[jj], fmaf(a.y, ph[16 + jj], ph[32 + jj]));
#pragma unroll
        for (int k = 0; k < 32; k++) {
            float rk = Rbuf[k][nl];
#pragma unroll
            for (int jj = 0; jj < 16; jj++) h[jj] = fmaf(rk, ph[48 + k * 16 + jj], h[jj]);
        }

        // z-gate matvec into g (reads Hbuf[cur], still intact)
#pragma unroll
        for (int jj = 0; jj < 16; jj++) g[jj] = fmaf(a.x, pz[jj], fmaf(a.y, pz[16 + jj], pz[32 + jj]));
#pragma unroll
        for (int k = 0; k < 32; k++) {
            float hk = Hbuf[cur][k][nl];
#pragma unroll
            for (int jj = 0; jj < 16; jj++) g[jj] = fmaf(hk, pz[48 + k * 16 + jj], g[jj]);
        }

        // combine; write new H into the other buffer
        float p = probs[t];
#pragma unroll
        for (int jj = 0; jj < 16; jj++) {
            float ht = ftanh(h[jj]);
            float z = fsig(g[jj]);
            float hn = fmaf(z, Hown[jj] - ht, ht);  // z*H + (1-z)*ht
            Hown[jj] = hn;
            acc[jj] = fmaf(p, hn, acc[jj]);
            Hbuf[cur ^ 1][qu * 16 + jj][nl] = hn;
        }
        __syncthreads();
        cur ^= 1;
    }

    if (valid) {
        float4* o = (float4*)(out + (size_t)node * 32 + qu * 16);
#pragma unroll
        for (int w = 0; w < 4; w++)
            o[w] = make_float4(acc[4 * w], acc[4 * w + 1], acc[4 * w + 2], acc[4 * w + 3]);
    }
}

extern "C" void kernel_launch(void* const* d_in, const int* in_sizes, int n_in,
                              void* d_out, int out_size, void* d_ws, size_t ws_size,
                              hipStream_t stream) {
    const float* X   = (const float*)d_in[0];
    const int*   idx = (const int*)d_in[1];
    const float* ew  = (const float*)d_in[2];
    const float* Wz  = (const float*)d_in[3];
    const float* bz  = (const float*)d_in[4];
    const float* Wr  = (const float*)d_in[5];
    const float* br  = (const float*)d_in[6];
    const float* Wh  = (const float*)d_in[7];
    const float* bh  = (const float*)d_in[8];
    const float* Lwz = (const float*)d_in[9];
    const float* Lbz = (const float*)d_in[10];
    const float* Lwr = (const float*)d_in[11];
    const float* Lbr = (const float*)d_in[12];
    const float* Lwh = (const float*)d_in[13];
    const float* Lbh = (const float*)d_in[14];
    const float* att = (const float*)d_in[15];

    float* ws   = (float*)d_ws;
    float* dinv = ws;
    float* AX   = ws + OFF_AX;
    float* P    = ws + OFF_P;
    int*   cnt  = (int*)ws + OFF_CNT;
    int*   off  = (int*)ws + OFF_OFF;
    int*   cur  = (int*)ws + OFF_CUR;
    int*   bsum = (int*)ws + OFF_BSUM;
    float* out  = (float*)d_out;
    int*   esrc = (int*)d_out;              // scratch inside d_out
    float* ewgt = (float*)d_out + EE;       // scratch inside d_out

    hipLaunchKernelGGL(k_zero, dim3((NN + 255) / 256), dim3(256), 0, stream, cnt);
    hipLaunchKernelGGL(k_count, dim3((EE + 255) / 256), dim3(256), 0, stream, idx, cnt);
    hipLaunchKernelGGL(k_scanA, dim3(NB_SCAN), dim3(512), 0, stream, cnt, off, bsum);
    hipLaunchKernelGGL(k_scanB, dim3(1), dim3(128), 0, stream, bsum);
    hipLaunchKernelGGL(k_scanC, dim3((NN + 255) / 256), dim3(256), 0, stream, off, bsum, cur);
    hipLaunchKernelGGL(k_fill, dim3((EE + 255) / 256), dim3(256), 0, stream, idx, ew, cur, esrc, ewgt);
    hipLaunchKernelGGL(k_degdinv, dim3((NN + 255) / 256), dim3(256), 0, stream, off, cnt, ewgt, dinv);
    hipLaunchKernelGGL(k_gather, dim3((BB * NN + 255) / 256), dim3(256), 0, stream,
                       X, dinv, esrc, ewgt, off, cnt, AX);
    hipLaunchKernelGGL(k_fold, dim3(1), dim3(128), 0, stream,
                       Wz, bz, Lwz, Lbz, Wr, br, Lwr, Lbr, Wh, bh, Lwh, Lbh, att, P);
    hipLaunchKernelGGL(k_recur, dim3((BB * NN + 63) / 64), dim3(128), 0, stream, AX, P, out);
}